// Round 11
// baseline (63.997 us; speedup 1.0000x reference)
//
#include <hip/hip_runtime.h>
#include <hip/hip_bf16.h>
#include <math.h>

#define NFREQ 1024      // N_FFT//2
#define NMELS 256
#define NNOTES 82
#define KPAD  96        // K padded to multiple of 32 for mfma 16x16x32
#define KMAXH 400

typedef __attribute__((ext_vector_type(8))) short bf16x8;
typedef __attribute__((ext_vector_type(4))) float f32x4;

__device__ inline unsigned short f2bf(float x) {
    union { float f; unsigned int u; } c; c.f = x;
    unsigned int r = c.u + 0x7FFFu + ((c.u >> 16) & 1u);   // round-to-nearest-even
    return (unsigned short)(r >> 16);
}

// ------------- Kernel AB (merged): harmonic cols (LDS) -> mel -> log -> bf16 ----
// Phase 2 in f32: its error (~1e-6 rel) is far below the bf16 rounding of w.
__global__ __launch_bounds__(256) void harm_prep(
    const float* __restrict__ omega,
    const float* __restrict__ stdv,
    const float* __restrict__ mask,
    unsigned short* __restrict__ wT)
{
    int n   = blockIdx.x;            // 0..95 (82..95 = K-pad rows)
    int tid = threadIdx.x;
    if (n >= NNOTES) {               // zero pad rows: (k>=82) x (any y bits) = 0
        wT[tid * KPAD + n] = 0;
        return;
    }
    __shared__ float cols[NFREQ];

    // phase 1: cols[fi] = sum_k omega*mask*gauss for this note
    float f0 = 27.5f * exp2f((float)n / 12.0f);
    for (int fi = tid; fi < NFREQ; fi += 256) {
        float f = 11025.0f * (float)fi / 1023.0f;
        const float RAD = 80.0f;                           // 16*sigma at sigma=5
        int klo = (int)ceilf((f - RAD) / f0);
        int khi = (int)floorf((f + RAD) / f0);
        if (klo < 1) klo = 1;
        if (khi > KMAXH) khi = KMAXH;
        float acc = 0.0f;
        for (int k = klo; k <= khi; ++k) {
            int idx = n * KMAXH + (k - 1);
            float mk = mask[idx];
            if (mk == 0.0f) continue;
            float c = f0 * (float)k;
            float s = stdv[idx];
            float d = (f - c) / s;
            float e = 0.5f * d * d;
            if (e > 90.0f) continue;
            acc += omega[idx] * mk * expf(-e);
        }
        cols[fi] = acc;
    }
    __syncthreads();

    // phase 2 (f32): mel triangle m = tid over LDS cols, log-compress, bf16
    int m = tid;
    const float logstep = 0.06875177742094911f;            // log(6.4)/27
    const float mel_max = 15.0f + logf(11.025f) / logstep; // hz_to_mel(11025)
    float mm0 = mel_max * (float)m       / 257.0f;
    float mm1 = mel_max * (float)(m + 1) / 257.0f;
    float mm2 = mel_max * (float)(m + 2) / 257.0f;
    float mf0 = (mm0 >= 15.0f) ? 1000.0f * expf(logstep * (mm0 - 15.0f)) : mm0 * (200.0f / 3.0f);
    float mf1 = (mm1 >= 15.0f) ? 1000.0f * expf(logstep * (mm1 - 15.0f)) : mm1 * (200.0f / 3.0f);
    float mf2 = (mm2 >= 15.0f) ? 1000.0f * expf(logstep * (mm2 - 15.0f)) : mm2 * (200.0f / 3.0f);
    float inv_lo = 1.0f / (mf1 - mf0);
    float inv_hi = 1.0f / (mf2 - mf1);
    float enorm  = 2.0f / (mf2 - mf0);
    int lo = (int)floorf(mf0 * (1024.0f / 11025.0f)) - 1;
    int hi = (int)ceilf (mf2 * (1024.0f / 11025.0f)) + 1;
    if (lo < 0) lo = 0;
    if (hi > 1023) hi = 1023;
    float acc = 0.0f;
    for (int fi = lo; fi <= hi; ++fi) {
        float ff = 11025.0f * (float)(fi + 1) / 1024.0f;
        float wt = fminf((ff - mf0) * inv_lo, (mf2 - ff) * inv_hi);
        wt = fmaxf(0.0f, wt) * enorm;
        acc += wt * cols[fi];
    }
    const float X_MIN = -13.815510557964274f;              // log(1e-6)
    const float X_MAX = 3.0f;
    float x = logf(acc + 1e-6f);
    x = fminf(fmaxf(x, X_MIN), X_MAX);
    wT[m * KPAD + n] = f2bf((x - X_MIN) * (1.0f / (X_MAX - X_MIN)));
}

// ---------------- Kernel C: out = y @ w, barrier-free wave pipelines ------------
// Wave = 16 rows x 64 cols; block = 4 waves stacked by row (64r x 64c tile).
// Each wave DMAs its OWN 16 y rows (5248 B, 16B-aligned) into a private LDS
// quarter via 6 global_load_lds dwordx4 -> only a wave-local vmcnt(0) wait,
// NO __syncthreads anywhere. k>=82 fragment elements are zeroed in-register
// (no cross-wave LDS reads). 4 col-blocks share a y stripe: XCD-chunked
// swizzle keeps them on one XCD so L2 serves the re-reads (FETCH stays ~43MB).
__device__ __forceinline__ void gload16(const void* g, void* l) {
    __builtin_amdgcn_global_load_lds(
        (const __attribute__((address_space(1))) unsigned int*)g,
        (__attribute__((address_space(3))) unsigned int*)l, 16, 0, 0);
}

__global__ __launch_bounds__(256) void harm_gemm(
    const float* __restrict__ y,
    const unsigned short* __restrict__ wT,
    float* __restrict__ out,
    int spx)                                   // stripes per XCD = (R/64)/8
{
    __shared__ float yf[4 * 1312 + 16];        // 4 wave-private 16x82 chunks
    int tid  = threadIdx.x;
    int lane = tid & 63;
    int wid  = tid >> 6;
    int r16  = lane & 15;
    int g4   = lane >> 4;

    // XCD-chunked swizzle: b&7 = xcd; 4 consecutive positions = 4 col-blocks
    // of the same 64-row stripe -> same XCD, temporally adjacent.
    int b      = blockIdx.x;
    int pos    = b >> 3;
    int stripe = (b & 7) * spx + (pos >> 2);
    int c0     = (pos & 3) * 64;
    size_t m0  = (size_t)stripe * 64;

    // ---- wave-private DMA: 16 rows = 328 x 16B units, 6 wave-instructions ----
    const float* ybase = y + (m0 + wid * 16) * NNOTES;     // 16B-aligned
    float* yfw = yf + wid * 1312;
    #pragma unroll
    for (int c = 0; c < 5; ++c)
        gload16(ybase + 4 * (c * 64 + lane), yfw + c * 256);
    if (lane < 8)
        gload16(ybase + 4 * (320 + lane), yfw + 1280);

    asm volatile("s_waitcnt vmcnt(0)" ::: "memory");       // wave-local drain
    __builtin_amdgcn_sched_barrier(0);

    // ---- B fragments: row r16 of this wave's chunk, k = kb*32 + g4*8 ----
    const float* yrow = yfw + r16 * NNOTES;
    bf16x8 ay[3];
    #pragma unroll
    for (int kb = 0; kb < 3; ++kb) {
        union { unsigned u[4]; bf16x8 v; } A;
        #pragma unroll
        for (int q = 0; q < 4; ++q) {
            int k0 = kb * 32 + g4 * 8 + 2 * q;             // even
            float2 a = (k0 + 1 < NNOTES) ? *(const float2*)(yrow + k0)
                                         : make_float2(0.f, 0.f);
            asm("v_cvt_pk_bf16_f32 %0, %1, %2" : "=v"(A.u[q]) : "v"(a.x), "v"(a.y));
        }
        ay[kb] = A.v;
    }

    // ---- per 16-col tile: load wT fragments (L1-broadcast), 3 MFMA, store ----
    #pragma unroll
    for (int ct = 0; ct < 4; ++ct) {
        const unsigned short* wp = wT + (size_t)(c0 + ct * 16 + r16) * KPAD + g4 * 8;
        bf16x8 b0 = *(const bf16x8*)(wp + 0);
        bf16x8 b1 = *(const bf16x8*)(wp + 32);
        bf16x8 b2 = *(const bf16x8*)(wp + 64);
        f32x4 acc = (f32x4){0.f, 0.f, 0.f, 0.f};
        acc = __builtin_amdgcn_mfma_f32_16x16x32_bf16(b0, ay[0], acc, 0, 0, 0);
        acc = __builtin_amdgcn_mfma_f32_16x16x32_bf16(b1, ay[1], acc, 0, 0, 0);
        acc = __builtin_amdgcn_mfma_f32_16x16x32_bf16(b2, ay[2], acc, 0, 0, 0);
        // lane holds out[row = m0+wid*16+r16][col = c0+ct*16+g4*4 .. +3]
        *(f32x4*)(out + (m0 + wid * 16 + r16) * NMELS + c0 + ct * 16 + g4 * 4) = acc;
    }
}

extern "C" void kernel_launch(void* const* d_in, const int* in_sizes, int n_in,
                              void* d_out, int out_size, void* d_ws, size_t ws_size,
                              hipStream_t stream) {
    const float* y     = (const float*)d_in[0];
    const float* omega = (const float*)d_in[1];
    const float* stdv  = (const float*)d_in[2];
    const float* mask  = (const float*)d_in[3];
    float* out = (float*)d_out;

    unsigned short* wT = (unsigned short*)d_ws;           // 256*96 bf16

    int R       = in_sizes[0] / NNOTES;                   // 131072 rows
    int stripes = R / 64;                                 // 2048
    int spx     = stripes / 8;                            // 256

    harm_prep<<<KPAD, 256, 0, stream>>>(omega, stdv, mask, wT);
    harm_gemm<<<stripes * 4, 256, 0, stream>>>(y, wT, out, spx);
}

// Round 12
// 61.775 us; speedup vs baseline: 1.0360x; 1.0360x over previous
//
#include <hip/hip_runtime.h>
#include <hip/hip_bf16.h>
#include <math.h>

#define NFREQ 1024      // N_FFT//2
#define NMELS 256
#define NNOTES 82
#define KPAD  96        // K padded to multiple of 32 for mfma 16x16x32
#define KMAXH 400

typedef __attribute__((ext_vector_type(8))) short bf16x8;
typedef __attribute__((ext_vector_type(4))) float f32x4;

__device__ inline unsigned short f2bf(float x) {
    union { float f; unsigned int u; } c; c.f = x;
    unsigned int r = c.u + 0x7FFFu + ((c.u >> 16) & 1u);   // round-to-nearest-even
    return (unsigned short)(r >> 16);
}

// ------------- Kernel AB (merged): harmonic cols (LDS) -> mel -> log -> bf16 ----
// Phase 2 in f32: its error (~1e-6 rel) is far below the bf16 rounding of w.
__global__ __launch_bounds__(256) void harm_prep(
    const float* __restrict__ omega,
    const float* __restrict__ stdv,
    const float* __restrict__ mask,
    unsigned short* __restrict__ wT)
{
    int n   = blockIdx.x;            // 0..95 (82..95 = K-pad rows)
    int tid = threadIdx.x;
    if (n >= NNOTES) {               // zero pad rows: (k>=82) x (any y bits) = 0
        wT[tid * KPAD + n] = 0;
        return;
    }
    __shared__ float cols[NFREQ];

    // phase 1: cols[fi] = sum_k omega*mask*gauss for this note
    float f0 = 27.5f * exp2f((float)n / 12.0f);
    for (int fi = tid; fi < NFREQ; fi += 256) {
        float f = 11025.0f * (float)fi / 1023.0f;
        const float RAD = 80.0f;                           // 16*sigma at sigma=5
        int klo = (int)ceilf((f - RAD) / f0);
        int khi = (int)floorf((f + RAD) / f0);
        if (klo < 1) klo = 1;
        if (khi > KMAXH) khi = KMAXH;
        float acc = 0.0f;
        for (int k = klo; k <= khi; ++k) {
            int idx = n * KMAXH + (k - 1);
            float mk = mask[idx];
            if (mk == 0.0f) continue;
            float c = f0 * (float)k;
            float s = stdv[idx];
            float d = (f - c) / s;
            float e = 0.5f * d * d;
            if (e > 90.0f) continue;
            acc += omega[idx] * mk * expf(-e);
        }
        cols[fi] = acc;
    }
    __syncthreads();

    // phase 2 (f32): mel triangle m = tid over LDS cols, log-compress, bf16
    int m = tid;
    const float logstep = 0.06875177742094911f;            // log(6.4)/27
    const float mel_max = 15.0f + logf(11.025f) / logstep; // hz_to_mel(11025)
    float mm0 = mel_max * (float)m       / 257.0f;
    float mm1 = mel_max * (float)(m + 1) / 257.0f;
    float mm2 = mel_max * (float)(m + 2) / 257.0f;
    float mf0 = (mm0 >= 15.0f) ? 1000.0f * expf(logstep * (mm0 - 15.0f)) : mm0 * (200.0f / 3.0f);
    float mf1 = (mm1 >= 15.0f) ? 1000.0f * expf(logstep * (mm1 - 15.0f)) : mm1 * (200.0f / 3.0f);
    float mf2 = (mm2 >= 15.0f) ? 1000.0f * expf(logstep * (mm2 - 15.0f)) : mm2 * (200.0f / 3.0f);
    float inv_lo = 1.0f / (mf1 - mf0);
    float inv_hi = 1.0f / (mf2 - mf1);
    float enorm  = 2.0f / (mf2 - mf0);
    int lo = (int)floorf(mf0 * (1024.0f / 11025.0f)) - 1;
    int hi = (int)ceilf (mf2 * (1024.0f / 11025.0f)) + 1;
    if (lo < 0) lo = 0;
    if (hi > 1023) hi = 1023;
    float acc = 0.0f;
    for (int fi = lo; fi <= hi; ++fi) {
        float ff = 11025.0f * (float)(fi + 1) / 1024.0f;
        float wt = fminf((ff - mf0) * inv_lo, (mf2 - ff) * inv_hi);
        wt = fmaxf(0.0f, wt) * enorm;
        acc += wt * cols[fi];
    }
    const float X_MIN = -13.815510557964274f;              // log(1e-6)
    const float X_MAX = 3.0f;
    float x = logf(acc + 1e-6f);
    x = fminf(fmaxf(x, X_MIN), X_MAX);
    wT[m * KPAD + n] = f2bf((x - X_MIN) * (1.0f / (X_MAX - X_MIN)));
}

// ---------------- Kernel C: out = y @ w, barrier-free, amplification-free -------
// Wave = 16 rows x 256 cols (FULL output width); block = 4 waves stacked by row
// (64-row stripe, y read exactly once -> no L2 read amplification). Each wave
// DMAs its own private 16x82 f32 chunk via 6 global_load_lds dwordx4 and waits
// only on its own vmcnt: ZERO __syncthreads. The y fragment (ay, 12 regs) is
// built once per wave and reused across all 16 column-tiles; w fragments
// stream from the 48 KB L1-resident wT. k>=82 is zero-predicated in-register.
__device__ __forceinline__ void gload16(const void* g, void* l) {
    __builtin_amdgcn_global_load_lds(
        (const __attribute__((address_space(1))) unsigned int*)g,
        (__attribute__((address_space(3))) unsigned int*)l, 16, 0, 0);
}

__global__ __launch_bounds__(256) void harm_gemm(
    const float* __restrict__ y,
    const unsigned short* __restrict__ wT,
    float* __restrict__ out)
{
    __shared__ float yf[4 * 1312];             // 4 wave-private 16x82 chunks
    int tid  = threadIdx.x;
    int lane = tid & 63;
    int wid  = tid >> 6;
    int r16  = lane & 15;
    int g4   = lane >> 4;
    size_t row0 = (size_t)blockIdx.x * 64 + wid * 16;

    // ---- wave-private DMA: 16 rows = 5248 f32 = 328 x 16B units ----
    const float* ybase = y + row0 * NNOTES;    // 16B-aligned (5248 % 4 == 0)
    float* yfw = yf + wid * 1312;
    #pragma unroll
    for (int c = 0; c < 5; ++c)
        gload16(ybase + 4 * (c * 64 + lane), yfw + c * 256);
    if (lane < 8)
        gload16(ybase + 4 * (320 + lane), yfw + 1280);

    asm volatile("s_waitcnt vmcnt(0)" ::: "memory");       // wave-local drain
    __builtin_amdgcn_sched_barrier(0);

    // ---- y fragment: row r16 of this wave's chunk, k = kb*32 + g4*8 ----
    const float* yrow = yfw + r16 * NNOTES;
    bf16x8 ay[3];
    #pragma unroll
    for (int kb = 0; kb < 3; ++kb) {
        union { unsigned u[4]; bf16x8 v; } A;
        #pragma unroll
        for (int q = 0; q < 4; ++q) {
            int k0 = kb * 32 + g4 * 8 + 2 * q;             // even
            float2 a = (k0 + 1 < NNOTES) ? *(const float2*)(yrow + k0)
                                         : make_float2(0.f, 0.f);
            asm("v_cvt_pk_bf16_f32 %0, %1, %2" : "=v"(A.u[q]) : "v"(a.x), "v"(a.y));
        }
        ay[kb] = A.v;
    }

    // ---- 16 column-tiles: stream w fragments, 3 MFMA each, store ----
    float* obase = out + (row0 + r16) * NMELS + g4 * 4;
    #pragma unroll 4
    for (int ct = 0; ct < 16; ++ct) {
        const unsigned short* wp = wT + (size_t)(ct * 16 + r16) * KPAD + g4 * 8;
        bf16x8 b0 = *(const bf16x8*)(wp + 0);
        bf16x8 b1 = *(const bf16x8*)(wp + 32);
        bf16x8 b2 = *(const bf16x8*)(wp + 64);
        f32x4 acc = (f32x4){0.f, 0.f, 0.f, 0.f};
        acc = __builtin_amdgcn_mfma_f32_16x16x32_bf16(b0, ay[0], acc, 0, 0, 0);
        acc = __builtin_amdgcn_mfma_f32_16x16x32_bf16(b1, ay[1], acc, 0, 0, 0);
        acc = __builtin_amdgcn_mfma_f32_16x16x32_bf16(b2, ay[2], acc, 0, 0, 0);
        // lane holds out[row0 + r16][ct*16 + g4*4 .. +3]
        *(f32x4*)(obase + ct * 16) = acc;
    }
}

extern "C" void kernel_launch(void* const* d_in, const int* in_sizes, int n_in,
                              void* d_out, int out_size, void* d_ws, size_t ws_size,
                              hipStream_t stream) {
    const float* y     = (const float*)d_in[0];
    const float* omega = (const float*)d_in[1];
    const float* stdv  = (const float*)d_in[2];
    const float* mask  = (const float*)d_in[3];
    float* out = (float*)d_out;

    unsigned short* wT = (unsigned short*)d_ws;           // 256*96 bf16

    int R = in_sizes[0] / NNOTES;                         // 131072 rows

    harm_prep<<<KPAD, 256, 0, stream>>>(omega, stdv, mask, wT);
    harm_gemm<<<R / 64, 256, 0, stream>>>(y, wT, out);
}

// Round 13
// 46.845 us; speedup vs baseline: 1.3661x; 1.3187x over previous
//
#include <hip/hip_runtime.h>
#include <hip/hip_bf16.h>
#include <math.h>

#define NFREQ 1024      // N_FFT//2
#define NMELS 256
#define NNOTES 82
#define KPAD  96        // K padded to multiple of 32 for mfma 16x16x32
#define KMAXH 400

typedef __attribute__((ext_vector_type(8))) short bf16x8;
typedef __attribute__((ext_vector_type(4))) float f32x4;

__device__ inline unsigned short f2bf(float x) {
    union { float f; unsigned int u; } c; c.f = x;
    unsigned int r = c.u + 0x7FFFu + ((c.u >> 16) & 1u);   // round-to-nearest-even
    return (unsigned short)(r >> 16);
}

// ------------- Kernel AB (merged): harmonic cols (LDS) -> mel -> log -> bf16 ----
__global__ __launch_bounds__(256) void harm_prep(
    const float* __restrict__ omega,
    const float* __restrict__ stdv,
    const float* __restrict__ mask,
    unsigned short* __restrict__ wT)
{
    int n   = blockIdx.x;            // 0..95 (82..95 = K-pad rows)
    int tid = threadIdx.x;
    if (n >= NNOTES) {               // zero pad rows: (k>=82) x (any y bits) = 0
        wT[tid * KPAD + n] = 0;
        return;
    }
    __shared__ float cols[NFREQ];

    // phase 1: cols[fi] = sum_k omega*mask*gauss for this note
    float f0 = 27.5f * exp2f((float)n / 12.0f);
    for (int fi = tid; fi < NFREQ; fi += 256) {
        float f = 11025.0f * (float)fi / 1023.0f;
        const float RAD = 80.0f;                           // 16*sigma at sigma=5
        int klo = (int)ceilf((f - RAD) / f0);
        int khi = (int)floorf((f + RAD) / f0);
        if (klo < 1) klo = 1;
        if (khi > KMAXH) khi = KMAXH;
        float acc = 0.0f;
        for (int k = klo; k <= khi; ++k) {
            int idx = n * KMAXH + (k - 1);
            float mk = mask[idx];
            if (mk == 0.0f) continue;
            float c = f0 * (float)k;
            float s = stdv[idx];
            float d = (f - c) / s;
            float e = 0.5f * d * d;
            if (e > 90.0f) continue;
            acc += omega[idx] * mk * expf(-e);
        }
        cols[fi] = acc;
    }
    __syncthreads();

    // phase 2 (f32): mel triangle m = tid over LDS cols, log-compress, bf16
    int m = tid;
    const float logstep = 0.06875177742094911f;            // log(6.4)/27
    const float mel_max = 15.0f + logf(11.025f) / logstep; // hz_to_mel(11025)
    float mm0 = mel_max * (float)m       / 257.0f;
    float mm1 = mel_max * (float)(m + 1) / 257.0f;
    float mm2 = mel_max * (float)(m + 2) / 257.0f;
    float mf0 = (mm0 >= 15.0f) ? 1000.0f * expf(logstep * (mm0 - 15.0f)) : mm0 * (200.0f / 3.0f);
    float mf1 = (mm1 >= 15.0f) ? 1000.0f * expf(logstep * (mm1 - 15.0f)) : mm1 * (200.0f / 3.0f);
    float mf2 = (mm2 >= 15.0f) ? 1000.0f * expf(logstep * (mm2 - 15.0f)) : mm2 * (200.0f / 3.0f);
    float inv_lo = 1.0f / (mf1 - mf0);
    float inv_hi = 1.0f / (mf2 - mf1);
    float enorm  = 2.0f / (mf2 - mf0);
    int lo = (int)floorf(mf0 * (1024.0f / 11025.0f)) - 1;
    int hi = (int)ceilf (mf2 * (1024.0f / 11025.0f)) + 1;
    if (lo < 0) lo = 0;
    if (hi > 1023) hi = 1023;
    float acc = 0.0f;
    for (int fi = lo; fi <= hi; ++fi) {
        float ff = 11025.0f * (float)(fi + 1) / 1024.0f;
        float wt = fminf((ff - mf0) * inv_lo, (mf2 - ff) * inv_hi);
        wt = fmaxf(0.0f, wt) * enorm;
        acc += wt * cols[fi];
    }
    const float X_MIN = -13.815510557964274f;              // log(1e-6)
    const float X_MAX = 3.0f;
    float x = logf(acc + 1e-6f);
    x = fminf(fmaxf(x, X_MIN), X_MAX);
    wT[m * KPAD + n] = f2bf((x - X_MIN) * (1.0f / (X_MAX - X_MIN)));
}

// ---------------- Kernel C: 2-tile DMA pipeline, counted vmcnt ------------------
// Block = 4 waves, 2 x (64 rows x 256 cols) tiles (rows 128b..128b+127).
// Issue order: 12 bw loads -> 6 DMA(t0)/wave -> 6 DMA(t1)/wave. Barrier-1 waits
// vmcnt(6): bw + t0 complete, t1's 6 DMAs STAY IN FLIGHT across the barrier
// (raw s_barrier; __syncthreads would drain vmcnt(0) and serialize the
// pipeline). Mid-barrier waits vmcnt(16): drains exactly t1's 6 oldest ops
// while tile-0's 16 just-issued stores remain outstanding. Zero staging VALU
// (f32 in LDS, cvt_pk at fragment read); k>=82 garbage x zero wT pad rows.
__device__ __forceinline__ void gload16(const void* g, void* l) {
    __builtin_amdgcn_global_load_lds(
        (const __attribute__((address_space(1))) unsigned int*)g,
        (__attribute__((address_space(3))) unsigned int*)l, 16, 0, 0);
}

__device__ __forceinline__ void compute_tile(
    const float* __restrict__ yfb, const bf16x8 bw[3][4],
    float* __restrict__ out, size_t rowbase, int r16, int g4, int c0)
{
    #pragma unroll
    for (int i = 0; i < 4; ++i) {
        const float* yrow = yfb + (i * 16 + r16) * NNOTES;
        bf16x8 ay[3];
        #pragma unroll
        for (int kb = 0; kb < 3; ++kb) {
            const float* fr = yrow + kb * 32 + g4 * 8;
            float2 a0 = *(const float2*)(fr + 0);
            float2 a1 = *(const float2*)(fr + 2);
            float2 a2 = *(const float2*)(fr + 4);
            float2 a3 = *(const float2*)(fr + 6);
            union { unsigned u[4]; bf16x8 v; } A;
            asm("v_cvt_pk_bf16_f32 %0, %1, %2" : "=v"(A.u[0]) : "v"(a0.x), "v"(a0.y));
            asm("v_cvt_pk_bf16_f32 %0, %1, %2" : "=v"(A.u[1]) : "v"(a1.x), "v"(a1.y));
            asm("v_cvt_pk_bf16_f32 %0, %1, %2" : "=v"(A.u[2]) : "v"(a2.x), "v"(a2.y));
            asm("v_cvt_pk_bf16_f32 %0, %1, %2" : "=v"(A.u[3]) : "v"(a3.x), "v"(a3.y));
            ay[kb] = A.v;
        }
        f32x4 acc[4];
        #pragma unroll
        for (int c = 0; c < 4; ++c) acc[c] = (f32x4){0.f, 0.f, 0.f, 0.f};
        #pragma unroll
        for (int kb = 0; kb < 3; ++kb)
            #pragma unroll
            for (int c = 0; c < 4; ++c)
                acc[c] = __builtin_amdgcn_mfma_f32_16x16x32_bf16(bw[kb][c], ay[kb], acc[c], 0, 0, 0);
        float* orow = out + (rowbase + i * 16 + r16) * NMELS + c0 + g4 * 4;
        #pragma unroll
        for (int c = 0; c < 4; ++c)
            *(f32x4*)(orow + c * 16) = acc[c];
    }
}

__global__ __launch_bounds__(256) void harm_gemm(
    const float* __restrict__ y,
    const unsigned short* __restrict__ wT,
    float* __restrict__ out)
{
    __shared__ float yf[2][5264];              // 2 x (64x82 f32 + 16 zero tail)
    int tid  = threadIdx.x;
    int lane = tid & 63;
    int wid  = tid >> 6;
    int r16  = lane & 15;
    int g4   = lane >> 4;
    int c0   = wid * 64;
    size_t row0 = (size_t)blockIdx.x * 128;

    // zero tails (visible to all waves after barrier-1's lgkmcnt(0))
    if (tid < 16) { yf[0][5248 + tid] = 0.f; yf[1][5248 + tid] = 0.f; }

    // ---- issue phase: bw (12 loads), DMA t0 (6/wave), DMA t1 (6/wave) ----
    bf16x8 bw[3][4];
    #pragma unroll
    for (int kb = 0; kb < 3; ++kb)
        #pragma unroll
        for (int c = 0; c < 4; ++c)
            bw[kb][c] = *(const bf16x8*)(wT + (size_t)(c0 + c * 16 + r16) * KPAD + kb * 32 + g4 * 8);
    __builtin_amdgcn_sched_barrier(0);

    {
        const float* yb0 = y + row0 * NNOTES;              // tile 0: 5248 f32
        int base = wid * 328;                              // 16B units, per-wave
        #pragma unroll
        for (int c = 0; c < 5; ++c)
            gload16(yb0 + 4 * (base + c * 64 + lane), &yf[0][(base + c * 64) * 4]);
        if (lane < 8)
            gload16(yb0 + 4 * (base + 320 + lane), &yf[0][(base + 320) * 4]);
        __builtin_amdgcn_sched_barrier(0);
        const float* yb1 = yb0 + 5248;                     // tile 1
        #pragma unroll
        for (int c = 0; c < 5; ++c)
            gload16(yb1 + 4 * (base + c * 64 + lane), &yf[1][(base + c * 64) * 4]);
        if (lane < 8)
            gload16(yb1 + 4 * (base + 320 + lane), &yf[1][(base + 320) * 4]);
    }

    // ---- barrier 1: bw + t0 done; t1's 6 DMAs stay in flight ----
    asm volatile("s_waitcnt vmcnt(6) lgkmcnt(0)" ::: "memory");
    __builtin_amdgcn_sched_barrier(0);
    __builtin_amdgcn_s_barrier();

    compute_tile(yf[0], bw, out, row0, r16, g4, c0);

    // ---- barrier 2: drain t1's 6 oldest; tile-0's 16 stores stay in flight ----
    asm volatile("s_waitcnt vmcnt(16)" ::: "memory");
    __builtin_amdgcn_sched_barrier(0);
    __builtin_amdgcn_s_barrier();

    compute_tile(yf[1], bw, out, row0 + 64, r16, g4, c0);
}

extern "C" void kernel_launch(void* const* d_in, const int* in_sizes, int n_in,
                              void* d_out, int out_size, void* d_ws, size_t ws_size,
                              hipStream_t stream) {
    const float* y     = (const float*)d_in[0];
    const float* omega = (const float*)d_in[1];
    const float* stdv  = (const float*)d_in[2];
    const float* mask  = (const float*)d_in[3];
    float* out = (float*)d_out;

    unsigned short* wT = (unsigned short*)d_ws;           // 256*96 bf16

    int R = in_sizes[0] / NNOTES;                         // 131072 rows

    harm_prep<<<KPAD, 256, 0, stream>>>(omega, stdv, mask, wT);
    harm_gemm<<<R / 128, 256, 0, stream>>>(y, wT, out);
}